// Round 8
// baseline (80.648 us; speedup 1.0000x reference)
//
#include <hip/hip_runtime.h>
#include <math.h>

// ---------- types ----------
typedef __bf16 bf16x8 __attribute__((ext_vector_type(8)));
typedef float f32x4 __attribute__((ext_vector_type(4)));
typedef float f32x16 __attribute__((ext_vector_type(16)));
typedef unsigned int u32x4 __attribute__((ext_vector_type(4)));
typedef unsigned short u16x8 __attribute__((ext_vector_type(8)));

#define B_ 4
#define T_ 4096
#define C_ 1024
#define H_ 128

static __device__ __forceinline__ unsigned short f32_to_bf16(float f) {
  unsigned int u = __builtin_bit_cast(unsigned int, f);
  u += 0x7FFFu + ((u >> 16) & 1u);   // RNE
  return (unsigned short)(u >> 16);
}
static __device__ __forceinline__ float bf16_to_f32(unsigned short u) {
  unsigned int x = ((unsigned int)u) << 16;
  return __builtin_bit_cast(float, x);
}

static __device__ __forceinline__ bf16x8 ld16g(const unsigned short* p) {
  return __builtin_bit_cast(bf16x8, *(const u32x4*)p);
}

static __device__ __forceinline__ f32x4 mfma16(bf16x8 a, bf16x8 b, f32x4 c) {
  return __builtin_amdgcn_mfma_f32_16x16x32_bf16(a, b, c, 0, 0, 0);
}
static __device__ __forceinline__ f32x16 mfma32(bf16x8 a, bf16x8 b, f32x16 c) {
  return __builtin_amdgcn_mfma_f32_32x32x16_bf16(a, b, c, 0, 0, 0);
}

// v_permlane32_swap_b32: ONLY safe when a and b hold DIFFERENT values
// (R4 bug: identical SSA values coalesce onto one VGPR and the swap no-ops).
static __device__ __forceinline__ void swapu(unsigned int& a, unsigned int& b) {
  asm volatile("v_permlane32_swap_b32 %0, %1" : "+v"(a), "+v"(b));
}
static __device__ __forceinline__ unsigned int cvtpk(float lo, float hi) {
  unsigned int r;
  asm("v_cvt_pk_bf16_f32 %0, %1, %2" : "=v"(r) : "v"(lo), "v"(hi));
  return r;
}
// single f32 -> bf16 via v_cvt_pk (RNE, 1 VALU op vs ~4 for the bit-twiddle)
static __device__ __forceinline__ unsigned short cvt1(float v) {
  return (unsigned short)cvtpk(v, v);
}
static __device__ __forceinline__ float bpermf(int addr, float v) {
  return __builtin_bit_cast(float, __builtin_amdgcn_ds_bpermute(addr, __builtin_bit_cast(int, v)));
}
static __device__ __forceinline__ float half_merge_max(float x) {
  return fmaxf(x, __shfl_xor(x, 32));
}
static __device__ __forceinline__ float half_merge_sum(float x) {
  return x + __shfl_xor(x, 32);
}
static __device__ __forceinline__ float vmax16(f32x16 v) {
  float a0 = fmaxf(v[0], v[1]),  a1 = fmaxf(v[2], v[3]);
  float a2 = fmaxf(v[4], v[5]),  a3 = fmaxf(v[6], v[7]);
  float a4 = fmaxf(v[8], v[9]),  a5 = fmaxf(v[10], v[11]);
  float a6 = fmaxf(v[12], v[13]), a7 = fmaxf(v[14], v[15]);
  float b0 = fmaxf(a0, a1), b1 = fmaxf(a2, a3), b2 = fmaxf(a4, a5), b3 = fmaxf(a6, a7);
  return fmaxf(fmaxf(b0, b1), fmaxf(b2, b3));
}
static __device__ __forceinline__ float vsum16(f32x16 v) {
  float a0 = v[0] + v[1],  a1 = v[2] + v[3],  a2 = v[4] + v[5],  a3 = v[6] + v[7];
  float a4 = v[8] + v[9],  a5 = v[10] + v[11], a6 = v[12] + v[13], a7 = v[14] + v[15];
  float b0 = a0 + a1, b1 = a2 + a3, b2 = a4 + a5, b3 = a6 + a7;
  return (b0 + b1) + (b2 + b3);
}

typedef __attribute__((address_space(1))) const unsigned char as1_u8;
typedef __attribute__((address_space(3))) unsigned char as3_u8;
static __device__ __forceinline__ void async16(const void* g, void* l) {
  __builtin_amdgcn_global_load_lds((as1_u8*)g, (as3_u8*)l, 16, 0, 0);
}

// 8 f32 -> 8 bf16 via 4x v_cvt_pk_bf16_f32 (RNE, element order preserved).
// Replaces pack8's ~32 VALU ops with 4.
static __device__ __forceinline__ u16x8 pack8cvt(float4 a, float4 b) {
  u32x4 u;
  u[0] = cvtpk(a.x, a.y); u[1] = cvtpk(a.z, a.w);
  u[2] = cvtpk(b.x, b.y); u[3] = cvtpk(b.z, b.w);
  return __builtin_bit_cast(u16x8, u);
}

#define PART_BYTES 33792   // bf16 O[128][128] (32768) + f32 m[128] (512) + f32 l[128] (512)

// ---------- kernel 1: W -> WT bf16 transposed; Wq scaled by log2e/sqrt(H) ----------
__global__ __launch_bounds__(256) void conv_w_kernel(const float* __restrict__ W0,
                                                     const float* __restrict__ W1,
                                                     const float* __restrict__ W2,
                                                     unsigned short* __restrict__ WT,
                                                     float qscale) {
  int tid = blockIdx.x * 256 + threadIdx.x;
  int o = tid >> 17;
  int r = tid & 131071;
  int n = r & 127;
  int k = r >> 7;
  const float* W = (o == 0) ? W0 : ((o == 1) ? W1 : W2);
  float v = W[r];
  if (o == 0) v *= qscale;
  WT[(size_t)o * 131072 + (size_t)n * 1024 + k] = f32_to_bf16(v);
}

// ---------- kernel 2: fused X-convert + QKV projection (128x128 tile, BK=64) ----------
// FROZEN at R3 config (session best, ~37-39us). Seven-experiment ledger:
// R1 (64-row/768blk)=60, R2 (counted-vmcnt dbuf)=40, R4 (LDS-free)=93,
// R5 (192-wide/256blk)=42, R6 (BK=128)=42, R7 (full QKV fusion, X read 1x)=~37
// — the sync-locked 128x128/BK64/384blk structure is this shape's plateau
// (~330 TF, consistent with the small-N shape curve). Do not re-open without
// a fundamentally different schedule.
__global__ __launch_bounds__(256) void qkv_fused_kernel(const float* __restrict__ X,
                                                        const unsigned short* __restrict__ WT,
                                                        unsigned short* __restrict__ Qb,
                                                        unsigned short* __restrict__ K3,
                                                        unsigned short* __restrict__ V3) {
  __shared__ __align__(16) unsigned short At[128 * 64];
  __shared__ __align__(16) unsigned short Bt[128 * 64];
  const int bid = blockIdx.x;
  const int xcd = bid & 7, ii = bid >> 3;   // ii 0..47
  const int o = ii % 3;
  const int tile = (ii / 3) * 8 + xcd;      // 0..127

  const float* Ax = X + (size_t)tile * 128 * 1024;
  const unsigned short* Bsrc = WT + (size_t)o * 131072;

  const int tid = threadIdx.x;
  const int lane = tid & 63, wid = tid >> 6;
  const int l15 = lane & 15, lg = lane >> 4;
  const int srow = wid * 8 + (lane >> 3);   // staging row within 32-row chunk
  const int scol = (lane & 7) * 8;          // staging col (elements)
  const int swcol = scol ^ ((srow & 7) << 3);             // A LDS write col (swizzled)
  const int sbcol = (((lane & 7) ^ (lane >> 3)) << 3);    // B global src col (pre-swizzle)
  const int wm = wid >> 1, wn = wid & 1;
  const int rsw = (l15 & 7) << 3;           // read-side XOR operand

  const f32x4 fzero = {0.f, 0.f, 0.f, 0.f};
  f32x4 acc[4][4];
#pragma unroll
  for (int i = 0; i < 4; i++)
#pragma unroll
    for (int j = 0; j < 4; j++) acc[i][j] = fzero;

  // A reg-prefetch for k-step 0
  float4 fA[4][2];
#pragma unroll
  for (int i4 = 0; i4 < 4; i4++) {
    const float* xs = Ax + (size_t)(i4 * 32 + srow) * 1024 + scol;
    fA[i4][0] = *(const float4*)xs;
    fA[i4][1] = *(const float4*)(xs + 4);
  }

  for (int ks = 0; ks < 16; ks++) {
    const int k0 = ks * 64;
    __syncthreads();   // previous MFMA LDS reads complete
    // stage B (async16, pre-swizzled global src -> swizzled LDS layout)
#pragma unroll
    for (int i4 = 0; i4 < 4; i4++)
      async16(Bsrc + (size_t)(i4 * 32 + srow) * 1024 + k0 + sbcol, &Bt[(i4 * 32 + wid * 8) * 64]);
    // stage A (convert + swizzled ds_write)
#pragma unroll
    for (int i4 = 0; i4 < 4; i4++) {
      const int row = i4 * 32 + srow;
      *(u16x8*)(&At[row * 64 + swcol]) = pack8cvt(fA[i4][0], fA[i4][1]);
    }
    __syncthreads();   // drains vmcnt (B) + lgkmcnt (A writes)
    // prefetch next k-step's A f32 (latency hidden under MFMA)
    if (ks + 1 < 16) {
#pragma unroll
      for (int i4 = 0; i4 < 4; i4++) {
        const float* xs = Ax + (size_t)(i4 * 32 + srow) * 1024 + (ks + 1) * 64 + scol;
        fA[i4][0] = *(const float4*)xs;
        fA[i4][1] = *(const float4*)(xs + 4);
      }
    }
#pragma unroll
    for (int kk = 0; kk < 2; kk++) {
      bf16x8 af[4], bfr[4];
#pragma unroll
      for (int i = 0; i < 4; i++)
        af[i] = ld16g(&At[(wm * 64 + i * 16 + l15) * 64 + ((kk * 32 + lg * 8) ^ rsw)]);
#pragma unroll
      for (int j = 0; j < 4; j++)
        bfr[j] = ld16g(&Bt[(wn * 64 + j * 16 + l15) * 64 + ((kk * 32 + lg * 8) ^ rsw)]);
      __builtin_amdgcn_s_setprio(1);
#pragma unroll
      for (int i = 0; i < 4; i++)
#pragma unroll
        for (int j = 0; j < 4; j++) acc[i][j] = mfma16(af[i], bfr[j], acc[i][j]);
      __builtin_amdgcn_s_setprio(0);
    }
  }

  if (o == 0) {
#pragma unroll
    for (int i = 0; i < 4; i++)
#pragma unroll
      for (int j = 0; j < 4; j++)
#pragma unroll
        for (int r = 0; r < 4; r++) {
          int row = tile * 128 + wm * 64 + i * 16 + lg * 4 + r;
          int col = wn * 64 + j * 16 + l15;
          Qb[(size_t)row * 128 + col] = cvt1(acc[i][j][r]);
        }
  } else if (o == 1) {
#pragma unroll
    for (int i = 0; i < 4; i++)
#pragma unroll
      for (int j = 0; j < 4; j++)
#pragma unroll
        for (int r = 0; r < 4; r++) {
          int token = tile * 128 + wm * 64 + i * 16 + lg * 4 + r;
          int d = wn * 64 + j * 16 + l15;
          int bb = token >> 12, t = token & 4095;
          int t32 = t >> 5;
          int lane2 = (t & 31) | (((d >> 3) & 1) << 5);
          int c = d >> 4;
          int j2 = d & 7;
          K3[(size_t)(((bb * 128 + t32) * 8 + c) * 64 + lane2) * 8 + j2] = cvt1(acc[i][j][r]);
        }
  } else {
    // V: acc row = token, col = d
#pragma unroll
    for (int i = 0; i < 4; i++)
#pragma unroll
      for (int j = 0; j < 4; j++)
#pragma unroll
        for (int r = 0; r < 4; r++) {
          int token = tile * 128 + wm * 64 + i * 16 + lg * 4 + r;
          int d = wn * 64 + j * 16 + l15;
          int bb = token >> 12, tt = token & 4095;
          int t32 = tt >> 5;
          int kss = (tt >> 4) & 1;
          int hi2 = (tt >> 3) & 1;
          int j2 = tt & 7;
          int dt = d >> 5;
          int lane2 = (d & 31) | (hi2 << 5);
          V3[(size_t)(((bb * 128 + t32) * 8 + dt * 2 + kss) * 64 + lane2) * 8 + j2] = cvt1(acc[i][j][r]);
        }
  }
}

// ---------- kernel 3: causal flash attention, 128-row blocks, shared KV tile ----------
// Grid 768 = 4b x 32 q-tiles(128 rows) x 6 kv-slots; 4 warps = 4 qg share one
// 32-token KV tile per round (16KB staging, 32KB dbuf). Counted vmcnt(4) + raw
// barriers (T3/T4); in-reg swapped-QK softmax + T12 P-pack + T13 defer-max.
// R8: __launch_bounds__(256,3) — grid 768 is EXACTLY 3 blocks/CU and the
// resources fit (LDS 3x32=96KB<160KB, VGPR 104<170 cap): all blocks become
// co-resident (no second dispatch wave) and 12 waves/CU overlap the per-round
// vmcnt/barrier stalls cross-block — the one stall-hiding mechanism this
// lockstep structure responds to.
// Partial: bf16 O + f32 m/l -> Pw; separate merge kernel combines (the fused
// last-block merge regressed 2.6x — __threadfence() = per-block L2 flush on
// non-coherent XCDs, R20 post-mortem).
__global__ __launch_bounds__(256, 3) void attn_kernel(const unsigned short* __restrict__ Qb,
                                                      const unsigned short* __restrict__ K3,
                                                      const unsigned short* __restrict__ V3,
                                                      unsigned char* __restrict__ Pw8) {
  const int bid = blockIdx.x;
  const int xcd = bid & 7;
  const int b = xcd >> 1;
  const int rest = bid >> 3;                  // 0..95
  const int h = rest % 6;                     // kv slot
  const int jj = rest / 6;                    // 0..15
  const int g = (xcd & 1) + 2 * (15 - jj);    // q-tile 0..31, heavy-first (LPT)

  const int tid = threadIdx.x;
  const int wid = tid >> 6, lane = tid & 63;
  const int l31 = lane & 31, hi = lane >> 5;
  const int qbase = g * 128 + wid * 32;

  __shared__ __align__(16) unsigned char LDSraw[32768];   // 2 x 16KB [K 8KB | V 8KB]
  unsigned short* lbuf = (unsigned short*)LDSraw;

  const unsigned short* K3b = K3 + (size_t)b * 524288;
  const unsigned short* V3b = V3 + (size_t)b * 524288;
  const int jmax_w = 4 * g + wid;
  const int Jcap = 4 * g + 3;
  const int R = (Jcap >= h) ? ((Jcap - h) / 6 + 1) : 0;

  const unsigned short* qp = Qb + ((size_t)(b * T_ + qbase + l31) << 7) + hi * 8;
  bf16x8 qf[8];
#pragma unroll
  for (int c = 0; c < 8; c++) qf[c] = ld16g(qp + c * 16);

  const f32x16 z16 = {0.f,0.f,0.f,0.f,0.f,0.f,0.f,0.f,0.f,0.f,0.f,0.f,0.f,0.f,0.f,0.f};
  f32x16 o[4];
  o[0] = z16; o[1] = z16; o[2] = z16; o[3] = z16;
  float m = -1e30f, l = 0.f;
  const int addrbase = hi << 4;

  const unsigned short* sbase = (wid < 2) ? K3b : V3b;
  const int soff = (wid & 1) * 2048;
  const int region = ((wid >= 2) ? 4096 : 0) + soff;

  if (R > 0) {
    const unsigned short* s0 = sbase + (size_t)h * 4096 + soff + lane * 8;
    unsigned short* d0 = lbuf + region;
#pragma unroll
    for (int i = 0; i < 4; i++) async16(s0 + i * 512, d0 + i * 512);
  }

  for (int r = 0; r < R; r++) {
    const int cur = r & 1;
    if (r + 1 < R) {
      const int jS = h + 6 * (r + 1);
      const unsigned short* sN = sbase + (size_t)jS * 4096 + soff + lane * 8;
      unsigned short* dN = lbuf + (cur ^ 1) * 8192 + region;
#pragma unroll
      for (int i = 0; i < 4; i++) async16(sN + i * 512, dN + i * 512);
      asm volatile("s_waitcnt vmcnt(4)" ::: "memory");
    } else {
      asm volatile("s_waitcnt vmcnt(0)" ::: "memory");
    }
    __builtin_amdgcn_s_barrier();

    const int j = h + 6 * r;
    if (j <= jmax_w) {
      const unsigned short* Kl = lbuf + cur * 8192;
      const unsigned short* Vl = Kl + 4096;
      bf16x8 kf[8];
#pragma unroll
      for (int c = 0; c < 8; c++) kf[c] = ld16g(Kl + c * 512 + lane * 8);
      f32x16 s = z16;
      __builtin_amdgcn_s_setprio(1);
#pragma unroll
      for (int c = 0; c < 8; c++) s = mfma32(kf[c], qf[c], s);
      __builtin_amdgcn_s_setprio(0);

      bf16x8 vf[4][2];
#pragma unroll
      for (int dt = 0; dt < 4; dt++)
#pragma unroll
        for (int ks = 0; ks < 2; ks++)
          vf[dt][ks] = ld16g(Vl + (dt * 2 + ks) * 512 + lane * 8);

      if (j == jmax_w) {
        const int kvb = j << 5;
        const int qq = qbase + l31;
#pragma unroll
        for (int r2 = 0; r2 < 16; r2++) {
          const int c0 = (r2 & 3) + 8 * (r2 >> 2) + 4 * hi;
          if (kvb + c0 > qq) s[r2] = -1e30f;
        }
      }

      float pm = half_merge_max(vmax16(s));
      const bool skip = __all(pm - m <= 8.0f);
      float mn = skip ? m : fmaxf(m, pm);
#pragma unroll
      for (int r2 = 0; r2 < 16; r2++) s[r2] = exp2f(s[r2] - mn);
      float ps = half_merge_sum(vsum16(s));
      if (skip) {
        l = l + ps;
      } else {
        float al = exp2f(m - mn);
        m = mn;
        l = l * al + ps;
#pragma unroll
        for (int r2 = 0; r2 < 16; r2++) {
          const int addr = addrbase + 4 * ((r2 & 3) + 8 * (r2 >> 2));
          float alb = bpermf(addr, al);
          o[0][r2] *= alb; o[1][r2] *= alb; o[2][r2] *= alb; o[3][r2] *= alb;
        }
      }

      bf16x8 pa[2];
#pragma unroll
      for (int ks = 0; ks < 2; ks++) {
        const int gb = ks * 8;
        unsigned int xa = cvtpk(s[gb + 0], s[gb + 1]), xb = cvtpk(s[gb + 4], s[gb + 5]);
        swapu(xa, xb);
        unsigned int ya = cvtpk(s[gb + 2], s[gb + 3]), yb = cvtpk(s[gb + 6], s[gb + 7]);
        swapu(ya, yb);
        u32x4 pw; pw[0] = xa; pw[1] = ya; pw[2] = xb; pw[3] = yb;
        pa[ks] = __builtin_bit_cast(bf16x8, pw);
      }

      __builtin_amdgcn_s_setprio(1);
#pragma unroll
      for (int ks = 0; ks < 2; ks++)
#pragma unroll
        for (int dt = 0; dt < 4; dt++) o[dt] = mfma32(pa[ks], vf[dt][ks], o[dt]);
      __builtin_amdgcn_s_setprio(0);
    }
    __builtin_amdgcn_sched_barrier(0);
    __builtin_amdgcn_s_barrier();
  }

  unsigned char* Pb = Pw8 + (size_t)((b * 32 + g) * 6 + h) * PART_BYTES;
  unsigned short* Po = (unsigned short*)Pb;
  float* Pm = (float*)(Pb + 32768);
  float* Pl = (float*)(Pb + 33280);
#pragma unroll
  for (int r2 = 0; r2 < 16; r2++) {
    const int q128 = wid * 32 + (r2 & 3) + 8 * (r2 >> 2) + 4 * hi;
#pragma unroll
    for (int dt = 0; dt < 4; dt++)
      Po[q128 * 128 + dt * 32 + l31] = cvt1(o[dt][r2]);
  }
  if (lane < 32) { Pm[wid * 32 + l31] = m; Pl[wid * 32 + l31] = l; }
}

// ---------- kernel 4: merge 6 kv-slot partials, normalize, write Out ----------
// XCD-aligned block swizzle: attn wrote tile tl's 6 partials on XCD
// xcd(tl) = (tl>>5)*2 + (tl&1); per-XCD partial footprint = 26MB/8 = 3.25MB
// < 4MB L2. Mapping merge blocks to the same XCD turns the Pw reads into L2
// hits instead of cross-XCD L3/HBM traffic.
__global__ __launch_bounds__(256) void attn_merge_kernel(const unsigned char* __restrict__ Pw8,
                                                         float* __restrict__ Out) {
  const int bid = blockIdx.x;                      // 0..2047
  const int xcd = bid & 7, idx = bid >> 3;         // idx 0..255
  const int b = xcd >> 1;                          // matches attn: b = xcd>>1
  const int g = ((idx >> 4) << 1) | (xcd & 1);     // matches attn: g&1 = xcd&1
  const int tl = b * 32 + g;                       // tile 0..127
  const int inner = (idx & 15) * 256 + threadIdx.x; // 0..4095
  const int q = inner >> 5;                        // 0..127
  const int d = (inner & 31) * 4;
  const unsigned char* base = Pw8 + (size_t)tl * 6 * PART_BYTES;

  float mm[6], ll[6];
#pragma unroll
  for (int p = 0; p < 6; p++) {
    mm[p] = *(const float*)(base + p * PART_BYTES + 32768 + q * 4);
    ll[p] = *(const float*)(base + p * PART_BYTES + 33280 + q * 4);
  }
  float mn = mm[0];
#pragma unroll
  for (int p = 1; p < 6; p++) mn = fmaxf(mn, mm[p]);
  float f[6], denom = 0.f;
#pragma unroll
  for (int p = 0; p < 6; p++) { f[p] = exp2f(mm[p] - mn); denom += f[p] * ll[p]; }
  const float inv = 1.0f / denom;

  f32x4 acc = {0.f, 0.f, 0.f, 0.f};
#pragma unroll
  for (int p = 0; p < 6; p++) {
    const unsigned short* po = (const unsigned short*)(base + p * PART_BYTES) + q * 128 + d;
    unsigned long long v4 = *(const unsigned long long*)po;
    const unsigned short* pv = (const unsigned short*)&v4;
#pragma unroll
    for (int i = 0; i < 4; i++) acc[i] += f[p] * bf16_to_f32(pv[i]);
  }
#pragma unroll
  for (int i = 0; i < 4; i++) acc[i] *= inv;
  *(f32x4*)(Out + (size_t)(b * 4096 + g * 128 + q) * 128 + d) = acc;
}

// ---------- host ----------
extern "C" void kernel_launch(void* const* d_in, const int* in_sizes, int n_in,
                              void* d_out, int out_size, void* d_ws, size_t ws_size,
                              hipStream_t stream) {
  const float* X  = (const float*)d_in[0];
  const float* W0 = (const float*)d_in[1];
  const float* W1 = (const float*)d_in[2];
  const float* W2 = (const float*)d_in[3];
  float* Out = (float*)d_out;

  unsigned char* ws = (unsigned char*)d_ws;
  // WT (786KB, dead after qkv_fused) overlaps Pw (26MB, written by attn).
  unsigned short* WT = (unsigned short*)(ws);
  unsigned char* Pw  = ws;                                 // 768*33792 = 25,952,256 B
  unsigned short* Qb = (unsigned short*)(ws + 34078720);   //  4,194,304 B
  unsigned short* K3 = (unsigned short*)(ws + 38273024);   //  4,194,304 B
  unsigned short* V3 = (unsigned short*)(ws + 42467328);   //  4,194,304 B (end 46.66MB)

  const float qscale = 1.4426950408889634f / sqrtf(128.0f); // log2(e) * H^-0.5

  conv_w_kernel<<<dim3(1536), dim3(256), 0, stream>>>(W0, W1, W2, WT, qscale);
  qkv_fused_kernel<<<dim3(384), dim3(256), 0, stream>>>(X, WT, Qb, K3, V3);
  attn_kernel<<<dim3(768), dim3(256), 0, stream>>>(Qb, K3, V3, Pw);
  attn_merge_kernel<<<dim3(2048), dim3(256), 0, stream>>>(Pw, Out);
}

// Round 9
// 71.972 us; speedup vs baseline: 1.1206x; 1.1206x over previous
//
#include <hip/hip_runtime.h>
#include <math.h>

// ---------- types ----------
typedef __bf16 bf16x8 __attribute__((ext_vector_type(8)));
typedef float f32x4 __attribute__((ext_vector_type(4)));
typedef float f32x16 __attribute__((ext_vector_type(16)));
typedef unsigned int u32x4 __attribute__((ext_vector_type(4)));
typedef unsigned short u16x8 __attribute__((ext_vector_type(8)));

#define B_ 4
#define T_ 4096
#define C_ 1024
#define H_ 128

static __device__ __forceinline__ unsigned short f32_to_bf16(float f) {
  unsigned int u = __builtin_bit_cast(unsigned int, f);
  u += 0x7FFFu + ((u >> 16) & 1u);   // RNE
  return (unsigned short)(u >> 16);
}
static __device__ __forceinline__ float bf16_to_f32(unsigned short u) {
  unsigned int x = ((unsigned int)u) << 16;
  return __builtin_bit_cast(float, x);
}

static __device__ __forceinline__ bf16x8 ld16g(const unsigned short* p) {
  return __builtin_bit_cast(bf16x8, *(const u32x4*)p);
}

static __device__ __forceinline__ f32x4 mfma16(bf16x8 a, bf16x8 b, f32x4 c) {
  return __builtin_amdgcn_mfma_f32_16x16x32_bf16(a, b, c, 0, 0, 0);
}
static __device__ __forceinline__ f32x16 mfma32(bf16x8 a, bf16x8 b, f32x16 c) {
  return __builtin_amdgcn_mfma_f32_32x32x16_bf16(a, b, c, 0, 0, 0);
}

// v_permlane32_swap_b32: ONLY safe when a and b hold DIFFERENT values
// (R4 bug: identical SSA values coalesce onto one VGPR and the swap no-ops).
static __device__ __forceinline__ void swapu(unsigned int& a, unsigned int& b) {
  asm volatile("v_permlane32_swap_b32 %0, %1" : "+v"(a), "+v"(b));
}
static __device__ __forceinline__ unsigned int cvtpk(float lo, float hi) {
  unsigned int r;
  asm("v_cvt_pk_bf16_f32 %0, %1, %2" : "=v"(r) : "v"(lo), "v"(hi));
  return r;
}
// single f32 -> bf16 via v_cvt_pk (RNE, 1 VALU op vs ~4 for the bit-twiddle)
static __device__ __forceinline__ unsigned short cvt1(float v) {
  return (unsigned short)cvtpk(v, v);
}
static __device__ __forceinline__ float bpermf(int addr, float v) {
  return __builtin_bit_cast(float, __builtin_amdgcn_ds_bpermute(addr, __builtin_bit_cast(int, v)));
}
static __device__ __forceinline__ float half_merge_max(float x) {
  return fmaxf(x, __shfl_xor(x, 32));
}
static __device__ __forceinline__ float half_merge_sum(float x) {
  return x + __shfl_xor(x, 32);
}
static __device__ __forceinline__ float vmax16(f32x16 v) {
  float a0 = fmaxf(v[0], v[1]),  a1 = fmaxf(v[2], v[3]);
  float a2 = fmaxf(v[4], v[5]),  a3 = fmaxf(v[6], v[7]);
  float a4 = fmaxf(v[8], v[9]),  a5 = fmaxf(v[10], v[11]);
  float a6 = fmaxf(v[12], v[13]), a7 = fmaxf(v[14], v[15]);
  float b0 = fmaxf(a0, a1), b1 = fmaxf(a2, a3), b2 = fmaxf(a4, a5), b3 = fmaxf(a6, a7);
  return fmaxf(fmaxf(b0, b1), fmaxf(b2, b3));
}
static __device__ __forceinline__ float vsum16(f32x16 v) {
  float a0 = v[0] + v[1],  a1 = v[2] + v[3],  a2 = v[4] + v[5],  a3 = v[6] + v[7];
  float a4 = v[8] + v[9],  a5 = v[10] + v[11], a6 = v[12] + v[13], a7 = v[14] + v[15];
  float b0 = a0 + a1, b1 = a2 + a3, b2 = a4 + a5, b3 = a6 + a7;
  return (b0 + b1) + (b2 + b3);
}

typedef __attribute__((address_space(1))) const unsigned char as1_u8;
typedef __attribute__((address_space(3))) unsigned char as3_u8;
static __device__ __forceinline__ void async16(const void* g, void* l) {
  __builtin_amdgcn_global_load_lds((as1_u8*)g, (as3_u8*)l, 16, 0, 0);
}

// 8 f32 -> 8 bf16 via 4x v_cvt_pk_bf16_f32 (RNE, element order preserved).
// Replaces pack8's ~32 VALU ops with 4.
static __device__ __forceinline__ u16x8 pack8cvt(float4 a, float4 b) {
  u32x4 u;
  u[0] = cvtpk(a.x, a.y); u[1] = cvtpk(a.z, a.w);
  u[2] = cvtpk(b.x, b.y); u[3] = cvtpk(b.z, b.w);
  return __builtin_bit_cast(u16x8, u);
}

#define PART_BYTES 33792   // bf16 O[128][128] (32768) + f32 m[128] (512) + f32 l[128] (512)

// ---------- kernel 1: W -> WT bf16 transposed; Wq scaled by log2e/sqrt(H) ----------
__global__ __launch_bounds__(256) void conv_w_kernel(const float* __restrict__ W0,
                                                     const float* __restrict__ W1,
                                                     const float* __restrict__ W2,
                                                     unsigned short* __restrict__ WT,
                                                     float qscale) {
  int tid = blockIdx.x * 256 + threadIdx.x;
  int o = tid >> 17;
  int r = tid & 131071;
  int n = r & 127;
  int k = r >> 7;
  const float* W = (o == 0) ? W0 : ((o == 1) ? W1 : W2);
  float v = W[r];
  if (o == 0) v *= qscale;
  WT[(size_t)o * 131072 + (size_t)n * 1024 + k] = f32_to_bf16(v);
}

// ---------- kernel 2: fused X-convert + QKV projection (128x128 tile, BK=64) ----------
// FROZEN at R3 config (session best). Seven-experiment ledger:
// R1 (64-row/768blk)=60, R2 (counted-vmcnt dbuf)=40, R4 (LDS-free)=93,
// R5 (192-wide/256blk)=42, R6 (BK=128)=42, R7 (full QKV fusion, X read 1x)=~37
// — the sync-locked 128x128/BK64/384blk structure is this shape's plateau
// (~330 TF, consistent with the small-N shape curve).
__global__ __launch_bounds__(256) void qkv_fused_kernel(const float* __restrict__ X,
                                                        const unsigned short* __restrict__ WT,
                                                        unsigned short* __restrict__ Qb,
                                                        unsigned short* __restrict__ K3,
                                                        unsigned short* __restrict__ V3) {
  __shared__ __align__(16) unsigned short At[128 * 64];
  __shared__ __align__(16) unsigned short Bt[128 * 64];
  const int bid = blockIdx.x;
  const int xcd = bid & 7, ii = bid >> 3;   // ii 0..47
  const int o = ii % 3;
  const int tile = (ii / 3) * 8 + xcd;      // 0..127

  const float* Ax = X + (size_t)tile * 128 * 1024;
  const unsigned short* Bsrc = WT + (size_t)o * 131072;

  const int tid = threadIdx.x;
  const int lane = tid & 63, wid = tid >> 6;
  const int l15 = lane & 15, lg = lane >> 4;
  const int srow = wid * 8 + (lane >> 3);   // staging row within 32-row chunk
  const int scol = (lane & 7) * 8;          // staging col (elements)
  const int swcol = scol ^ ((srow & 7) << 3);             // A LDS write col (swizzled)
  const int sbcol = (((lane & 7) ^ (lane >> 3)) << 3);    // B global src col (pre-swizzle)
  const int wm = wid >> 1, wn = wid & 1;
  const int rsw = (l15 & 7) << 3;           // read-side XOR operand

  const f32x4 fzero = {0.f, 0.f, 0.f, 0.f};
  f32x4 acc[4][4];
#pragma unroll
  for (int i = 0; i < 4; i++)
#pragma unroll
    for (int j = 0; j < 4; j++) acc[i][j] = fzero;

  // A reg-prefetch for k-step 0
  float4 fA[4][2];
#pragma unroll
  for (int i4 = 0; i4 < 4; i4++) {
    const float* xs = Ax + (size_t)(i4 * 32 + srow) * 1024 + scol;
    fA[i4][0] = *(const float4*)xs;
    fA[i4][1] = *(const float4*)(xs + 4);
  }

  for (int ks = 0; ks < 16; ks++) {
    const int k0 = ks * 64;
    __syncthreads();   // previous MFMA LDS reads complete
    // stage B (async16, pre-swizzled global src -> swizzled LDS layout)
#pragma unroll
    for (int i4 = 0; i4 < 4; i4++)
      async16(Bsrc + (size_t)(i4 * 32 + srow) * 1024 + k0 + sbcol, &Bt[(i4 * 32 + wid * 8) * 64]);
    // stage A (convert + swizzled ds_write)
#pragma unroll
    for (int i4 = 0; i4 < 4; i4++) {
      const int row = i4 * 32 + srow;
      *(u16x8*)(&At[row * 64 + swcol]) = pack8cvt(fA[i4][0], fA[i4][1]);
    }
    __syncthreads();   // drains vmcnt (B) + lgkmcnt (A writes)
    // prefetch next k-step's A f32 (latency hidden under MFMA)
    if (ks + 1 < 16) {
#pragma unroll
      for (int i4 = 0; i4 < 4; i4++) {
        const float* xs = Ax + (size_t)(i4 * 32 + srow) * 1024 + (ks + 1) * 64 + scol;
        fA[i4][0] = *(const float4*)xs;
        fA[i4][1] = *(const float4*)(xs + 4);
      }
    }
#pragma unroll
    for (int kk = 0; kk < 2; kk++) {
      bf16x8 af[4], bfr[4];
#pragma unroll
      for (int i = 0; i < 4; i++)
        af[i] = ld16g(&At[(wm * 64 + i * 16 + l15) * 64 + ((kk * 32 + lg * 8) ^ rsw)]);
#pragma unroll
      for (int j = 0; j < 4; j++)
        bfr[j] = ld16g(&Bt[(wn * 64 + j * 16 + l15) * 64 + ((kk * 32 + lg * 8) ^ rsw)]);
      __builtin_amdgcn_s_setprio(1);
#pragma unroll
      for (int i = 0; i < 4; i++)
#pragma unroll
        for (int j = 0; j < 4; j++) acc[i][j] = mfma16(af[i], bfr[j], acc[i][j]);
      __builtin_amdgcn_s_setprio(0);
    }
  }

  if (o == 0) {
#pragma unroll
    for (int i = 0; i < 4; i++)
#pragma unroll
      for (int j = 0; j < 4; j++)
#pragma unroll
        for (int r = 0; r < 4; r++) {
          int row = tile * 128 + wm * 64 + i * 16 + lg * 4 + r;
          int col = wn * 64 + j * 16 + l15;
          Qb[(size_t)row * 128 + col] = cvt1(acc[i][j][r]);
        }
  } else if (o == 1) {
#pragma unroll
    for (int i = 0; i < 4; i++)
#pragma unroll
      for (int j = 0; j < 4; j++)
#pragma unroll
        for (int r = 0; r < 4; r++) {
          int token = tile * 128 + wm * 64 + i * 16 + lg * 4 + r;
          int d = wn * 64 + j * 16 + l15;
          int bb = token >> 12, t = token & 4095;
          int t32 = t >> 5;
          int lane2 = (t & 31) | (((d >> 3) & 1) << 5);
          int c = d >> 4;
          int j2 = d & 7;
          K3[(size_t)(((bb * 128 + t32) * 8 + c) * 64 + lane2) * 8 + j2] = cvt1(acc[i][j][r]);
        }
  } else {
    // V: acc row = token, col = d
#pragma unroll
    for (int i = 0; i < 4; i++)
#pragma unroll
      for (int j = 0; j < 4; j++)
#pragma unroll
        for (int r = 0; r < 4; r++) {
          int token = tile * 128 + wm * 64 + i * 16 + lg * 4 + r;
          int d = wn * 64 + j * 16 + l15;
          int bb = token >> 12, tt = token & 4095;
          int t32 = tt >> 5;
          int kss = (tt >> 4) & 1;
          int hi2 = (tt >> 3) & 1;
          int j2 = tt & 7;
          int dt = d >> 5;
          int lane2 = (d & 31) | (hi2 << 5);
          V3[(size_t)(((bb * 128 + t32) * 8 + dt * 2 + kss) * 64 + lane2) * 8 + j2] = cvt1(acc[i][j][r]);
        }
  }
}

// ---------- kernel 3: causal flash attention, 128-row blocks, shared KV tile ----------
// Grid 768 = 4b x 32 q-tiles(128 rows) x 6 kv-slots; 4 warps = 4 qg share one
// 32-token KV tile per round (16KB staging, 32KB dbuf). Counted vmcnt(4) + raw
// barriers (T3/T4); in-reg swapped-QK softmax + T12 P-pack + T13 defer-max.
// __launch_bounds__(256,2): R8 measured that (256,3) makes the compiler
// throttle VGPRs 104->84 (rematerialization) and REGRESSES attn ~30->47us —
// the (256,2)/104-VGPR schedule is the measured best. Do not re-raise.
// Partial: bf16 O + f32 m/l -> Pw; separate merge kernel combines (the fused
// last-block merge regressed 2.6x — __threadfence() = per-block L2 flush on
// non-coherent XCDs, R20 post-mortem).
__global__ __launch_bounds__(256, 2) void attn_kernel(const unsigned short* __restrict__ Qb,
                                                      const unsigned short* __restrict__ K3,
                                                      const unsigned short* __restrict__ V3,
                                                      unsigned char* __restrict__ Pw8) {
  const int bid = blockIdx.x;
  const int xcd = bid & 7;
  const int b = xcd >> 1;
  const int rest = bid >> 3;                  // 0..95
  const int h = rest % 6;                     // kv slot
  const int jj = rest / 6;                    // 0..15
  const int g = (xcd & 1) + 2 * (15 - jj);    // q-tile 0..31, heavy-first (LPT)

  const int tid = threadIdx.x;
  const int wid = tid >> 6, lane = tid & 63;
  const int l31 = lane & 31, hi = lane >> 5;
  const int qbase = g * 128 + wid * 32;

  __shared__ __align__(16) unsigned char LDSraw[32768];   // 2 x 16KB [K 8KB | V 8KB]
  unsigned short* lbuf = (unsigned short*)LDSraw;

  const unsigned short* K3b = K3 + (size_t)b * 524288;
  const unsigned short* V3b = V3 + (size_t)b * 524288;
  const int jmax_w = 4 * g + wid;
  const int Jcap = 4 * g + 3;
  const int R = (Jcap >= h) ? ((Jcap - h) / 6 + 1) : 0;

  const unsigned short* qp = Qb + ((size_t)(b * T_ + qbase + l31) << 7) + hi * 8;
  bf16x8 qf[8];
#pragma unroll
  for (int c = 0; c < 8; c++) qf[c] = ld16g(qp + c * 16);

  const f32x16 z16 = {0.f,0.f,0.f,0.f,0.f,0.f,0.f,0.f,0.f,0.f,0.f,0.f,0.f,0.f,0.f,0.f};
  f32x16 o[4];
  o[0] = z16; o[1] = z16; o[2] = z16; o[3] = z16;
  float m = -1e30f, l = 0.f;
  const int addrbase = hi << 4;

  const unsigned short* sbase = (wid < 2) ? K3b : V3b;
  const int soff = (wid & 1) * 2048;
  const int region = ((wid >= 2) ? 4096 : 0) + soff;

  if (R > 0) {
    const unsigned short* s0 = sbase + (size_t)h * 4096 + soff + lane * 8;
    unsigned short* d0 = lbuf + region;
#pragma unroll
    for (int i = 0; i < 4; i++) async16(s0 + i * 512, d0 + i * 512);
  }

  for (int r = 0; r < R; r++) {
    const int cur = r & 1;
    if (r + 1 < R) {
      const int jS = h + 6 * (r + 1);
      const unsigned short* sN = sbase + (size_t)jS * 4096 + soff + lane * 8;
      unsigned short* dN = lbuf + (cur ^ 1) * 8192 + region;
#pragma unroll
      for (int i = 0; i < 4; i++) async16(sN + i * 512, dN + i * 512);
      asm volatile("s_waitcnt vmcnt(4)" ::: "memory");
    } else {
      asm volatile("s_waitcnt vmcnt(0)" ::: "memory");
    }
    __builtin_amdgcn_s_barrier();

    const int j = h + 6 * r;
    if (j <= jmax_w) {
      const unsigned short* Kl = lbuf + cur * 8192;
      const unsigned short* Vl = Kl + 4096;
      bf16x8 kf[8];
#pragma unroll
      for (int c = 0; c < 8; c++) kf[c] = ld16g(Kl + c * 512 + lane * 8);
      f32x16 s = z16;
      __builtin_amdgcn_s_setprio(1);
#pragma unroll
      for (int c = 0; c < 8; c++) s = mfma32(kf[c], qf[c], s);
      __builtin_amdgcn_s_setprio(0);

      bf16x8 vf[4][2];
#pragma unroll
      for (int dt = 0; dt < 4; dt++)
#pragma unroll
        for (int ks = 0; ks < 2; ks++)
          vf[dt][ks] = ld16g(Vl + (dt * 2 + ks) * 512 + lane * 8);

      if (j == jmax_w) {
        const int kvb = j << 5;
        const int qq = qbase + l31;
#pragma unroll
        for (int r2 = 0; r2 < 16; r2++) {
          const int c0 = (r2 & 3) + 8 * (r2 >> 2) + 4 * hi;
          if (kvb + c0 > qq) s[r2] = -1e30f;
        }
      }

      float pm = half_merge_max(vmax16(s));
      const bool skip = __all(pm - m <= 8.0f);
      float mn = skip ? m : fmaxf(m, pm);
#pragma unroll
      for (int r2 = 0; r2 < 16; r2++) s[r2] = exp2f(s[r2] - mn);
      float ps = half_merge_sum(vsum16(s));
      if (skip) {
        l = l + ps;
      } else {
        float al = exp2f(m - mn);
        m = mn;
        l = l * al + ps;
#pragma unroll
        for (int r2 = 0; r2 < 16; r2++) {
          const int addr = addrbase + 4 * ((r2 & 3) + 8 * (r2 >> 2));
          float alb = bpermf(addr, al);
          o[0][r2] *= alb; o[1][r2] *= alb; o[2][r2] *= alb; o[3][r2] *= alb;
        }
      }

      bf16x8 pa[2];
#pragma unroll
      for (int ks = 0; ks < 2; ks++) {
        const int gb = ks * 8;
        unsigned int xa = cvtpk(s[gb + 0], s[gb + 1]), xb = cvtpk(s[gb + 4], s[gb + 5]);
        swapu(xa, xb);
        unsigned int ya = cvtpk(s[gb + 2], s[gb + 3]), yb = cvtpk(s[gb + 6], s[gb + 7]);
        swapu(ya, yb);
        u32x4 pw; pw[0] = xa; pw[1] = ya; pw[2] = xb; pw[3] = yb;
        pa[ks] = __builtin_bit_cast(bf16x8, pw);
      }

      __builtin_amdgcn_s_setprio(1);
#pragma unroll
      for (int ks = 0; ks < 2; ks++)
#pragma unroll
        for (int dt = 0; dt < 4; dt++) o[dt] = mfma32(pa[ks], vf[dt][ks], o[dt]);
      __builtin_amdgcn_s_setprio(0);
    }
    __builtin_amdgcn_sched_barrier(0);
    __builtin_amdgcn_s_barrier();
  }

  unsigned char* Pb = Pw8 + (size_t)((b * 32 + g) * 6 + h) * PART_BYTES;
  unsigned short* Po = (unsigned short*)Pb;
  float* Pm = (float*)(Pb + 32768);
  float* Pl = (float*)(Pb + 33280);
#pragma unroll
  for (int r2 = 0; r2 < 16; r2++) {
    const int q128 = wid * 32 + (r2 & 3) + 8 * (r2 >> 2) + 4 * hi;
#pragma unroll
    for (int dt = 0; dt < 4; dt++)
      Po[q128 * 128 + dt * 32 + l31] = cvt1(o[dt][r2]);
  }
  if (lane < 32) { Pm[wid * 32 + l31] = m; Pl[wid * 32 + l31] = l; }
}

// ---------- kernel 4: merge 6 kv-slot partials, normalize, write Out ----------
// XCD-aligned block swizzle: attn wrote tile tl's 6 partials on XCD
// xcd(tl) = (tl>>5)*2 + (tl&1); per-XCD partial footprint = 26MB/8 = 3.25MB
// < 4MB L2. Mapping merge blocks to the same XCD turns the Pw reads into L2
// hits instead of cross-XCD L3/HBM traffic.
__global__ __launch_bounds__(256) void attn_merge_kernel(const unsigned char* __restrict__ Pw8,
                                                         float* __restrict__ Out) {
  const int bid = blockIdx.x;                      // 0..2047
  const int xcd = bid & 7, idx = bid >> 3;         // idx 0..255
  const int b = xcd >> 1;                          // matches attn: b = xcd>>1
  const int g = ((idx >> 4) << 1) | (xcd & 1);     // matches attn: g&1 = xcd&1
  const int tl = b * 32 + g;                       // tile 0..127
  const int inner = (idx & 15) * 256 + threadIdx.x; // 0..4095
  const int q = inner >> 5;                        // 0..127
  const int d = (inner & 31) * 4;
  const unsigned char* base = Pw8 + (size_t)tl * 6 * PART_BYTES;

  float mm[6], ll[6];
#pragma unroll
  for (int p = 0; p < 6; p++) {
    mm[p] = *(const float*)(base + p * PART_BYTES + 32768 + q * 4);
    ll[p] = *(const float*)(base + p * PART_BYTES + 33280 + q * 4);
  }
  float mn = mm[0];
#pragma unroll
  for (int p = 1; p < 6; p++) mn = fmaxf(mn, mm[p]);
  float f[6], denom = 0.f;
#pragma unroll
  for (int p = 0; p < 6; p++) { f[p] = exp2f(mm[p] - mn); denom += f[p] * ll[p]; }
  const float inv = 1.0f / denom;

  f32x4 acc = {0.f, 0.f, 0.f, 0.f};
#pragma unroll
  for (int p = 0; p < 6; p++) {
    const unsigned short* po = (const unsigned short*)(base + p * PART_BYTES) + q * 128 + d;
    unsigned long long v4 = *(const unsigned long long*)po;
    const unsigned short* pv = (const unsigned short*)&v4;
#pragma unroll
    for (int i = 0; i < 4; i++) acc[i] += f[p] * bf16_to_f32(pv[i]);
  }
#pragma unroll
  for (int i = 0; i < 4; i++) acc[i] *= inv;
  *(f32x4*)(Out + (size_t)(b * 4096 + g * 128 + q) * 128 + d) = acc;
}

// ---------- host ----------
extern "C" void kernel_launch(void* const* d_in, const int* in_sizes, int n_in,
                              void* d_out, int out_size, void* d_ws, size_t ws_size,
                              hipStream_t stream) {
  const float* X  = (const float*)d_in[0];
  const float* W0 = (const float*)d_in[1];
  const float* W1 = (const float*)d_in[2];
  const float* W2 = (const float*)d_in[3];
  float* Out = (float*)d_out;

  unsigned char* ws = (unsigned char*)d_ws;
  // WT (786KB, dead after qkv_fused) overlaps Pw (26MB, written by attn).
  unsigned short* WT = (unsigned short*)(ws);
  unsigned char* Pw  = ws;                                 // 768*33792 = 25,952,256 B
  unsigned short* Qb = (unsigned short*)(ws + 34078720);   //  4,194,304 B
  unsigned short* K3 = (unsigned short*)(ws + 38273024);   //  4,194,304 B
  unsigned short* V3 = (unsigned short*)(ws + 42467328);   //  4,194,304 B (end 46.66MB)

  const float qscale = 1.4426950408889634f / sqrtf(128.0f); // log2(e) * H^-0.5

  conv_w_kernel<<<dim3(1536), dim3(256), 0, stream>>>(W0, W1, W2, WT, qscale);
  qkv_fused_kernel<<<dim3(384), dim3(256), 0, stream>>>(X, WT, Qb, K3, V3);
  attn_kernel<<<dim3(768), dim3(256), 0, stream>>>(Qb, K3, V3, Pw);
  attn_merge_kernel<<<dim3(2048), dim3(256), 0, stream>>>(Pw, Out);
}